// Round 4
// baseline (132.329 us; speedup 1.0000x reference)
//
#include <hip/hip_runtime.h>
#include <cstddef>

#define NEXP  45
#define DIM   256
#define KCH   64     // output dims per block (lane = k)
#define NTOK  4096
#define GRP   6      // tokens per wave-group
#define NWAVE 8

// Zero d_out (harness re-poisons to 0xAA before every timed launch; first
// correctness call's d_out state is unspecified -> must zero explicitly).
__global__ void pos_zero_kernel(float* out) { out[threadIdx.x] = 0.0f; }

// Grid: 45 experts * 4 out-chunks = 180 blocks, 512 threads (8 waves).
// Per block: compact token list for expert e, stage W[e][k0:k0+64][:] transposed
// in LDS, then waves process 6-token groups with W reused across tokens.
// x reads are wave-uniform (readfirstlane'd token index): SGPR base + literal
// offset -> broadcast/scalar loads, no per-iteration VALU address math.
// W-LDS reads use literal ds offsets under unroll-8. ReLU+max folded into a
// running max (accumulator floor 0 == relu floor).
__global__ __launch_bounds__(512, 1)
void pos_expert_kernel(const float* __restrict__ x, const int* __restrict__ tags,
                       const float* __restrict__ W, const float* __restrict__ bias,
                       float* __restrict__ out) {
  __shared__ alignas(16) float WT[64 * DIM];   // [d0][k][c] = W[e][k0+k][4*d0+c], 64 KB
  __shared__ int   list[NTOK];                 // 16 KB (worst-case capacity)
  __shared__ float wmax[NWAVE][KCH];           // 2 KB
  __shared__ int   cnt;

  const int tid  = threadIdx.x;
  const int lane = tid & 63;
  const int wv   = tid >> 6;
  const int e    = blockIdx.x >> 2;
  const int k0   = (blockIdx.x & 3) * KCH;

  if (tid == 0) cnt = 0;
  __syncthreads();

  // ---- compact this expert's token indices (order irrelevant under max).
  for (int n = tid; n < NTOK; n += 512) {
    if (tags[n] == e) list[atomicAdd(&cnt, 1)] = n;
  }

  // ---- stage W chunk transposed. Thread = (row k=lane, col-block d0=wv*8+r).
  // ds_write_b128 at byte (d0*64+lane)*16: per-lane-contiguous 16B -> conflict-
  // free. Global side: 1KB-strided 16B reads; r=0..3 share a 64B line back-to-
  // back (MSHR-merged), so L2 traffic ~= 64KB/block (the chunk itself).
  {
    const float* Wrow = W + ((size_t)e * DIM + k0 + lane) * DIM;
#pragma unroll
    for (int r = 0; r < 8; ++r) {
      const int d0 = (wv << 3) + r;
      const float4 v = *(const float4*)(Wrow + (d0 << 2));
      *(float4*)&WT[((d0 << 6) + lane) << 2] = v;
    }
  }
  __syncthreads();   // covers list/cnt (compaction) and WT (staging)

  const int   m  = cnt;
  const float bk = bias[(size_t)e * DIM + k0 + lane];
  float mx = 0.0f;   // relu floor: every contribution is max'ed against 0

  for (int g0 = wv * GRP; g0 < m; g0 += NWAVE * GRP) {
    const int nt = (m - g0 < GRP) ? (m - g0) : GRP;

    // wave-uniform token row pointers (SGPR base per token)
    const float4* xp[GRP];
#pragma unroll
    for (int j = 0; j < GRP; ++j) {
      const int idx = (j < nt) ? (g0 + j) : g0;   // tail: duplicate token 0, discarded below
      const int n   = __builtin_amdgcn_readfirstlane(list[idx]);
      xp[j] = (const float4*)(x + (size_t)n * DIM);
    }

    float a[GRP];
#pragma unroll
    for (int j = 0; j < GRP; ++j) a[j] = 0.0f;

    // Per d0: 1 ds_read_b128 (imm offset) + 6 uniform global loads (imm
    // offsets) + 24 FMA. unroll-8 (not 16): halves peak load live-ranges
    // (~224 VGPR worst case, inside the 256-VGPR/2-wave-per-SIMD budget)
    // while keeping imm-offset folding and 56-load ILP windows.
#pragma unroll 8
    for (int d0 = 0; d0 < 64; ++d0) {
      const float4 w4 = *(const float4*)&WT[((d0 << 6) + lane) << 2];
#pragma unroll
      for (int j = 0; j < GRP; ++j) {
        const float4 xv = xp[j][d0];
        a[j] += w4.x * xv.x + w4.y * xv.y + w4.z * xv.z + w4.w * xv.w;
      }
    }

#pragma unroll
    for (int j = 0; j < GRP; ++j)
      if (j < nt) mx = fmaxf(mx, a[j] + bk);
  }

  wmax[wv][lane] = mx;
  __syncthreads();
  if (tid < KCH) {
    float v = wmax[0][tid];
#pragma unroll
    for (int w = 1; w < NWAVE; ++w) v = fmaxf(v, wmax[w][tid]);
    // all values >= 0: int-bit compare is monotone; out zeroed by pos_zero_kernel
    atomicMax((int*)out + k0 + tid, __float_as_int(v));
  }
}

extern "C" void kernel_launch(void* const* d_in, const int* in_sizes, int n_in,
                              void* d_out, int out_size, void* d_ws, size_t ws_size,
                              hipStream_t stream) {
  const float* x    = (const float*)d_in[0];
  const int*   tags = (const int*)d_in[1];
  const float* W    = (const float*)d_in[2];
  const float* b    = (const float*)d_in[3];
  float*       out  = (float*)d_out;

  pos_zero_kernel<<<1, 256, 0, stream>>>(out);
  pos_expert_kernel<<<NEXP * 4, 512, 0, stream>>>(x, tags, W, b, out);
}